// Round 14
// baseline (122.816 us; speedup 1.0000x reference)
//
#include <hip/hip_runtime.h>

// ETNN layer, N=50000 cells, HID=64, DEG=16 neighbors, 4 nodes/cell, sp=3.
//
// Bilinear split of the per-pair message MLP:
//   x@W1 = f_i@W1[0:64] + f_j@W1[64:128] + geom*W1[128]
// -> wswz    : weight pre-swizzle ONLY (tiny first graph node, 96 blocks)
// -> prep    : block-split: [0,782) feat fp32->bf16 (featb) + Q = feat@W1bot
//              as fp8 e4m3 (64B rows); [782,1368) positions passthrough;
//              [1368,1564) centroids. (pos/cent feed only msg_tail — next
//              launch — so folding them here keeps the critical path legal.)
// -> msg_tail: FUSED, block = one 16-cell tile (3125 blocks, 4 waves):
//      phase 0: P-tile^T = W1top^T x X^T (MFMA from featb) -> LDS (bf16)
//      phase A: per wave 4 cells (setup hoisted for ILP): geom inline,
//               s = mean_d silu(P+Q[nbr]+g*w1L+b1) -> overwrites P in LDS
//      phase B: msg^T = W2^T x s^T (+b2) -> LDS; hu^T = Wu1^T x [feat|msg]^T
//               (+bu1, silu) -> LDS; out = hu x Wu2 + bu2 + feat.
//
// MFMA layouts (HW-verified): A[m=lane&15][k=quad*8+j], B[k=quad*8+j][n=lane&15],
// D[row=quad*4+reg][col=lane&15].

#define DEG 16

typedef __attribute__((ext_vector_type(8))) short short8;   // 8 bf16
typedef __attribute__((ext_vector_type(4))) float f32x4;    // MFMA acc
typedef uint2 uint2_a __attribute__((may_alias));
typedef uint4 uint4_a __attribute__((may_alias));
typedef unsigned short ushort_a __attribute__((may_alias));

union HbRd { uint4_a u; short8 s; };
union Frag { short8 s; uint4 u; };

__device__ __forceinline__ unsigned f2bf(float f) {
  unsigned u = __float_as_uint(f);
  return (u + 0x7FFFu + ((u >> 16) & 1u)) >> 16;   // RNE fp32->bf16
}
__device__ __forceinline__ float bf2f(unsigned bits16) {
  return __uint_as_float(bits16 << 16);
}
__device__ __forceinline__ float silu(float h) {
  return h / (1.f + __expf(-h));
}
__device__ __forceinline__ float silu_fast(float h) {
  return h * __builtin_amdgcn_rcpf(1.f + __expf(-h));
}

// ---------------------------------------------------------------- wswz ----
// 24576 threads: weight pre-swizzle into MFMA fragment order.
__global__ __launch_bounds__(256) void wswz_kernel(
    const float* __restrict__ W1, const float* __restrict__ W2,
    const float* __restrict__ Wu1, const float* __restrict__ Wu2,
    unsigned short* __restrict__ w1pq, unsigned short* __restrict__ w2t,
    unsigned short* __restrict__ wu1t, unsigned short* __restrict__ wu2b)
{
  const int r = blockIdx.x * 256 + threadIdx.x;
  if (r < 8192) {
    // w1pq: A-frags of [W1top|W1bot]^T, [mt 0..7][kk 0..1]
    const int j = r & 7, l = (r >> 3) & 15, q = (r >> 7) & 3;
    const int f = r >> 9, kk = f & 1, mt = f >> 1;
    const int k = kk * 32 + q * 8 + j;        // feat dim 0..63
    const int m = mt * 16 + l;                // pq col 0..127
    w1pq[r] = (unsigned short)f2bf(
        (m < 64) ? W1[k * 64 + m] : W1[(k + 64) * 64 + (m - 64)]);
  } else if (r < 12288) {
    // w2t: A-frags of W2^T, [mt 0..3][kk 0..1]
    const int s = r - 8192;
    const int j = s & 7, l = (s >> 3) & 15, q = (s >> 7) & 3;
    const int f = s >> 9, kk = f & 1, mt = f >> 1;
    const int k = kk * 32 + q * 8 + j;
    w2t[s] = (unsigned short)f2bf(W2[k * 64 + mt * 16 + l]);
  } else if (r < 20480) {
    // wu1t: A-frags of Wu1^T, [mt 0..3][kk 0..3]
    const int s = r - 12288;
    const int j = s & 7, l = (s >> 3) & 15, q = (s >> 7) & 3;
    const int f = s >> 9, kk = f & 3, mt = f >> 2;
    const int k = kk * 32 + q * 8 + j;        // 0..127
    wu1t[s] = (unsigned short)f2bf(Wu1[k * 64 + mt * 16 + l]);
  } else if (r < 24576) {
    // wu2b: B-frags of Wu2, [nt 0..3][kk 0..1]
    const int s = r - 20480;
    const int j = s & 7, l = (s >> 3) & 15, q = (s >> 7) & 3;
    const int f = s >> 9, kk = f & 1, nt = f >> 1;
    const int k = kk * 32 + q * 8 + j;
    wu2b[s] = (unsigned short)f2bf(Wu2[k * 64 + nt * 16 + l]);
  }
}

// ---------------------------------------------------------------- prep ----
// blocks [0,782): per-16-cell tile: feat fp32->bf16 (featb + frags),
//   Q^T = W1bot^T x X^T -> fp8 e4m3 (HW cvt), 64B rows.
// blocks [782,1368): positions passthrough (float4).
// blocks [1368,1564): centroid of each cell's 4 nodes -> cent4.
__global__ __launch_bounds__(256) void prep_kernel(
    const float* __restrict__ feat, const float* __restrict__ pos,
    const unsigned short* __restrict__ w1pq,
    unsigned short* __restrict__ featb,
    unsigned char* __restrict__ Q8,
    float* __restrict__ outpos, float* __restrict__ cent4)
{
  const int b = blockIdx.x;
  if (b >= 1368) {
    const int i = (b - 1368) * 256 + threadIdx.x;
    if (i < 50000) {
      const float4* pp = (const float4*)(pos + 12 * i);   // 48B rows
      const float4 a = pp[0], bb = pp[1], c = pp[2];
      float4 o;
      o.x = (a.x + a.w + bb.z + c.y) * 0.25f;
      o.y = (a.y + bb.x + bb.w + c.z) * 0.25f;
      o.z = (a.z + bb.y + c.x + c.w) * 0.25f;
      o.w = 0.f;
      ((float4*)cent4)[i] = o;
    }
    return;
  }
  if (b >= 782) {
    const int t = (b - 782) * 256 + threadIdx.x;
    if (t < 150000) ((float4*)outpos)[t] = ((const float4*)pos)[t];
    return;
  }

  const int lane = threadIdx.x & 63;
  const int wid  = threadIdx.x >> 6;
  const int quad = lane >> 4;
  const int l15  = lane & 15;
  const int tile = b * 4 + wid;
  const bool act = (tile < 3125);
  const int  tt  = act ? tile : 3124;
  const int  cr  = tt * 16 + l15;

  // feat rows -> bf16 frags (B-layout) + featb store
  short8 xf[2];
  #pragma unroll
  for (int kk = 0; kk < 2; ++kk) {
    const float4 f0 = *(const float4*)(feat + cr * 64 + kk * 32 + quad * 8);
    const float4 f1 = *(const float4*)(feat + cr * 64 + kk * 32 + quad * 8 + 4);
    Frag v;
    v.s[0] = (short)f2bf(f0.x); v.s[1] = (short)f2bf(f0.y);
    v.s[2] = (short)f2bf(f0.z); v.s[3] = (short)f2bf(f0.w);
    v.s[4] = (short)f2bf(f1.x); v.s[5] = (short)f2bf(f1.y);
    v.s[6] = (short)f2bf(f1.z); v.s[7] = (short)f2bf(f1.w);
    xf[kk] = v.s;
    if (act) *(uint4*)(featb + cr * 64 + kk * 32 + quad * 8) = v.u;
  }

  // Q = bottom half of [P|Q]: w1pq mt = 4..7
  short8 wf[4][2];
  #pragma unroll
  for (int m = 0; m < 4; ++m)
    #pragma unroll
    for (int kk = 0; kk < 2; ++kk)
      wf[m][kk] = *(const short8*)(w1pq + ((((m + 4) * 2 + kk) * 4 + quad) << 7) + l15 * 8);

  f32x4 acc[4] = {};
  #pragma unroll
  for (int kk = 0; kk < 2; ++kk)
    #pragma unroll
    for (int m = 0; m < 4; ++m)
      acc[m] = __builtin_amdgcn_mfma_f32_16x16x32_bf16(wf[m][kk], xf[kk], acc[m], 0, 0, 0);

  if (act) {
    #pragma unroll
    for (int m = 0; m < 4; ++m) {          // Q: fp8 e4m3 (HW cvt pair)
      int w = __builtin_amdgcn_cvt_pk_fp8_f32(acc[m][0], acc[m][1], 0, false);
      w = __builtin_amdgcn_cvt_pk_fp8_f32(acc[m][2], acc[m][3], w, true);
      *(unsigned int*)(Q8 + cr * 64 + m * 16 + quad * 4) = (unsigned)w;
    }
  }
}

// ------------------------------------------------------------ msg_tail ----
// One block per 16-cell tile (3125 blocks, 4 waves).
__global__ __launch_bounds__(256) void msg_tail_kernel(
    const unsigned short* __restrict__ featb,
    const unsigned char* __restrict__ Q8,
    const float4* __restrict__ cent4,
    const int* __restrict__ nbr,
    const float* __restrict__ feat,
    const unsigned short* __restrict__ w1pq,
    const unsigned short* __restrict__ w2t,
    const unsigned short* __restrict__ wu1t,
    const unsigned short* __restrict__ wu2b,
    const float* __restrict__ b1, const float* __restrict__ W1,
    const float* __restrict__ b2, const float* __restrict__ bu1,
    const float* __restrict__ bu2,
    float* __restrict__ outf)
{
  __shared__ uint4 smem[432];   // sT (P then s) 16x144B | Msg 16x144B | Hb 16x144B
  char* sT  = (char*)smem;
  char* Msg = sT + 2304;
  char* Hb  = sT + 4608;

  const int lane = threadIdx.x & 63;
  const int wid  = threadIdx.x >> 6;
  const int quad = lane >> 4;
  const int l15  = lane & 15;
  const int tile = blockIdx.x;
  const int cr   = tile * 16 + l15;

  // ---- phase 0: P-tile^T = W1top^T x X^T (mt = wid) -> LDS bf16 ----
  {
    short8 wpf[2];
    #pragma unroll
    for (int kk = 0; kk < 2; ++kk)
      wpf[kk] = *(const short8*)(w1pq + (((wid * 2 + kk) * 4 + quad) << 7) + l15 * 8);
    f32x4 accp = {};
    #pragma unroll
    for (int kk = 0; kk < 2; ++kk) {
      const short8 bf = *(const short8*)(featb + cr * 64 + kk * 32 + quad * 8);
      accp = __builtin_amdgcn_mfma_f32_16x16x32_bf16(wpf[kk], bf, accp, 0, 0, 0);
    }
    uint2 pk;
    pk.x = f2bf(accp[0]) | (f2bf(accp[1]) << 16);
    pk.y = f2bf(accp[2]) | (f2bf(accp[3]) << 16);
    *(uint2_a*)(sT + l15 * 144 + wid * 32 + quad * 8) = pk;
  }

  __syncthreads();

  // ---- phase A: gather 4 cells per wave; setup hoisted for ILP ----
  const float b1l = b1[lane];
  const float wl  = W1[8192 + lane];

  const int*  nrow[4];
  float g4[4];
  #pragma unroll
  for (int i = 0; i < 4; ++i) {
    const int cs = __builtin_amdgcn_readfirstlane(tile * 16 + wid * 4 + i);
    nrow[i] = nbr + cs * DEG;
    const int njl = nrow[i][lane & 15];
    const float4 ci = cent4[cs];           // uniform -> s_load
    const float4 cj = cent4[njl];          // random 16B gather
    const float dx = ci.x - cj.x, dy = ci.y - cj.y, dz = ci.z - cj.z;
    g4[i] = sqrtf(dx * dx + dy * dy + dz * dz);
  }

  #pragma unroll
  for (int i = 0; i < 4; ++i) {
    const float pcb =
        bf2f(((const ushort_a*)(sT + (wid * 4 + i) * 144))[lane]) + b1l;
    const float g = g4[i];

    float acc = 0.f;
    #pragma unroll
    for (int d = 0; d < DEG; ++d) {
      const int   nd = nrow[i][d];         // uniform -> s_load
      const float gd = __uint_as_float(
          __builtin_amdgcn_readlane((int)__float_as_uint(g), d));
      const float qv = __builtin_amdgcn_cvt_f32_fp8((int)Q8[nd * 64 + lane], 0);
      acc += silu_fast(pcb + qv + gd * wl);
    }
    // overwrite own P row with s (only this wave reads this row's P)
    ((ushort_a*)(sT + (wid * 4 + i) * 144))[lane] =
        (unsigned short)f2bf(acc * 0.0625f);
  }

  // wave w's weight frags (mt/nt = wid only)
  short8 w2f[2], wu1f[4], wu2f[2];
  #pragma unroll
  for (int kk = 0; kk < 2; ++kk)
    w2f[kk]  = *(const short8*)(w2t  + (((wid * 2 + kk) * 4 + quad) << 7) + l15 * 8);
  #pragma unroll
  for (int kk = 0; kk < 4; ++kk)
    wu1f[kk] = *(const short8*)(wu1t + (((wid * 4 + kk) * 4 + quad) << 7) + l15 * 8);
  #pragma unroll
  for (int kk = 0; kk < 2; ++kk)
    wu2f[kk] = *(const short8*)(wu2b + (((wid * 2 + kk) * 4 + quad) << 7) + l15 * 8);

  const f32x4 b2f  = *(const f32x4*)(b2  + wid * 16 + quad * 4);
  const f32x4 bu1f = *(const f32x4*)(bu1 + wid * 16 + quad * 4);
  const float bu2v = bu2[wid * 16 + l15];

  __syncthreads();

  // ---- stage 1: msg^T = W2^T x s^T (+b2), mt = wid ----
  f32x4 accm = {};
  #pragma unroll
  for (int kk = 0; kk < 2; ++kk) {
    HbRd t; t.u = *(const uint4_a*)(sT + l15 * 144 + kk * 64 + quad * 16);
    accm = __builtin_amdgcn_mfma_f32_16x16x32_bf16(w2f[kk], t.s, accm, 0, 0, 0);
  }
  {
    uint2 pk;
    pk.x = f2bf(accm[0] + b2f[0]) | (f2bf(accm[1] + b2f[1]) << 16);
    pk.y = f2bf(accm[2] + b2f[2]) | (f2bf(accm[3] + b2f[3]) << 16);
    *(uint2_a*)(Msg + l15 * 144 + wid * 32 + quad * 8) = pk;
  }
  __syncthreads();

  // ---- stage 2: hu^T = Wu1^T x [feat|msg]^T (+bu1, silu), mt = wid ----
  f32x4 accu = {};
  #pragma unroll
  for (int kk = 0; kk < 4; ++kk) {
    short8 bf;
    if (kk < 2) {
      bf = *(const short8*)(featb + cr * 64 + kk * 32 + quad * 8);
    } else {
      HbRd t; t.u = *(const uint4_a*)(Msg + l15 * 144 + (kk - 2) * 64 + quad * 16);
      bf = t.s;
    }
    accu = __builtin_amdgcn_mfma_f32_16x16x32_bf16(wu1f[kk], bf, accu, 0, 0, 0);
  }
  {
    float sv[4];
    #pragma unroll
    for (int rg = 0; rg < 4; ++rg)
      sv[rg] = silu(accu[rg] + bu1f[rg]);
    uint2 pk;
    pk.x = f2bf(sv[0]) | (f2bf(sv[1]) << 16);
    pk.y = f2bf(sv[2]) | (f2bf(sv[3]) << 16);
    *(uint2_a*)(Hb + l15 * 144 + wid * 32 + quad * 8) = pk;
  }
  __syncthreads();

  // ---- stage 3: out = hu x Wu2 + bu2 + feat, nt = wid ----
  f32x4 acc2 = {};
  #pragma unroll
  for (int kk = 0; kk < 2; ++kk) {
    HbRd t; t.u = *(const uint4_a*)(Hb + l15 * 144 + kk * 64 + quad * 16);
    acc2 = __builtin_amdgcn_mfma_f32_16x16x32_bf16(t.s, wu2f[kk], acc2, 0, 0, 0);
  }
  #pragma unroll
  for (int rg = 0; rg < 4; ++rg) {
    const int row = tile * 16 + quad * 4 + rg;
    const int col = wid * 16 + l15;
    outf[row * 64 + col] = feat[row * 64 + col] + acc2[rg] + bu2v;
  }
}

// -------------------------------------------------------------- launch ----
extern "C" void kernel_launch(void* const* d_in, const int* in_sizes, int n_in,
                              void* d_out, int out_size, void* d_ws, size_t ws_size,
                              hipStream_t stream)
{
  const float* feat = (const float*)d_in[0];
  const float* pos  = (const float*)d_in[1];
  const int*   nbr  = (const int*)d_in[2];
  const float* W1   = (const float*)d_in[3];
  const float* b1   = (const float*)d_in[4];
  const float* W2   = (const float*)d_in[5];
  const float* b2   = (const float*)d_in[6];
  const float* Wu1  = (const float*)d_in[7];
  const float* bu1  = (const float*)d_in[8];
  const float* Wu2  = (const float*)d_in[9];
  const float* bu2  = (const float*)d_in[10];
  float* out = (float*)d_out;

  // ws: featb 6.4M @0 | Q8 fp8 3.2M @12.8M | cent4 0.8M @25.6M
  //   | swizzled weights @26.4M
  unsigned short* featb = (unsigned short*)d_ws;
  unsigned char*  Q8    = (unsigned char*)((char*)d_ws + 12800000);
  float*          cent4 = (float*)((char*)d_ws + 25600000);
  unsigned short* w1pq  = (unsigned short*)((char*)d_ws + 26400000);
  unsigned short* w2t   = (unsigned short*)((char*)d_ws + 26416384);
  unsigned short* wu1t  = (unsigned short*)((char*)d_ws + 26424576);
  unsigned short* wu2b  = (unsigned short*)((char*)d_ws + 26440960);

  wswz_kernel<<<96, 256, 0, stream>>>(W1, W2, Wu1, Wu2,
                                      w1pq, w2t, wu1t, wu2b);
  prep_kernel<<<1564, 256, 0, stream>>>(feat, pos, w1pq, featb, Q8,
                                        out + 3200000, cent4);
  msg_tail_kernel<<<3125, 256, 0, stream>>>(featb, Q8, (const float4*)cent4,
                                            nbr, feat, w1pq, w2t, wu1t, wu2b,
                                            b1, W1, b2, bu1, bu2, out);
}